// Round 7
// baseline (390.865 us; speedup 1.0000x reference)
//
#include <hip/hip_runtime.h>

static constexpr int F_IN = 128;
static constexpr int H1 = 32;
static constexpr int TPB = 256;
// slice-major tables: T[slice][node][8], slice = feat>>3 (4 slices, 3.2 MB each -> L2-resident)

// ---------------- degree count (int) ----------------
__global__ void deg_kernel(const int* __restrict__ dst, int* __restrict__ degi, int E) {
    for (int i = blockIdx.x * blockDim.x + threadIdx.x; i < E; i += gridDim.x * blockDim.x)
        atomicAdd(&degi[dst[i]], 1);
}

// ---------------- prefix scan (3 passes) for CSR rowptr ----------------
__global__ void scan1(const int* __restrict__ degi, int* __restrict__ bsum, int N) {
    __shared__ int sh[TPB];
    int i = blockIdx.x * TPB + threadIdx.x;
    sh[threadIdx.x] = (i < N) ? degi[i] : 0;
    __syncthreads();
    for (int o = TPB / 2; o > 0; o >>= 1) {
        if (threadIdx.x < o) sh[threadIdx.x] += sh[threadIdx.x + o];
        __syncthreads();
    }
    if (threadIdx.x == 0) bsum[blockIdx.x] = sh[0];
}

__global__ void scan2(int* __restrict__ bsum, int nb) {  // nb <= 512, one block of 512
    __shared__ int sh[512];
    int t = threadIdx.x;
    int orig = (t < nb) ? bsum[t] : 0;
    sh[t] = orig;
    __syncthreads();
    for (int o = 1; o < 512; o <<= 1) {
        int v = (t >= o) ? sh[t - o] : 0;
        __syncthreads();
        sh[t] += v;
        __syncthreads();
    }
    if (t < nb) bsum[t] = sh[t] - orig;  // exclusive
}

__global__ void scan3(const int* __restrict__ degi, const int* __restrict__ bsum,
                      int* __restrict__ rowptr, int* __restrict__ cursor,
                      float* __restrict__ dinv, int N) {
    __shared__ int sh[TPB];
    int i = blockIdx.x * TPB + threadIdx.x;
    int t = threadIdx.x;
    int d = (i < N) ? degi[i] : 0;
    sh[t] = d;
    __syncthreads();
    for (int o = 1; o < TPB; o <<= 1) {
        int v = (t >= o) ? sh[t - o] : 0;
        __syncthreads();
        sh[t] += v;
        __syncthreads();
    }
    if (i < N) {
        int excl = sh[t] - d + bsum[blockIdx.x];
        rowptr[i] = excl;
        cursor[i] = excl;
        dinv[i] = 1.0f / sqrtf((float)d + 1.0f);  // deg incl. self-loop
    }
}

// ---------------- CSR fill, XCD-bucketed (round 6, kept) ----------------
__global__ void fill_bucketed(const int* __restrict__ src, const int* __restrict__ dst,
                              int* __restrict__ cursor, int* __restrict__ csr_src,
                              int E, int N) {
    const int r = blockIdx.x & 7;
    const int b8 = blockIdx.x >> 3;
    const int nb8 = gridDim.x >> 3;
    const int chunk = N >> 3;
    const int lo = r * chunk;
    const int hi = (r == 7) ? N : lo + chunk;
    for (int i = b8 * blockDim.x + threadIdx.x; i < E; i += nb8 * blockDim.x) {
        int d = dst[i];
        if (d >= lo && d < hi) {
            int slot = atomicAdd(&cursor[d], 1);
            csr_src[slot] = src[i];
        }
    }
}

// ---------------- fold W3 @ W_lin -> w3l[64], w3l[64] = beta ----------------
__global__ void prep_kernel(const float* __restrict__ W3, const float* __restrict__ b3,
                            const float* __restrict__ Wl, const float* __restrict__ bl,
                            float* __restrict__ w3l) {
    int j = threadIdx.x;  // 64 threads
    float acc = 0.0f;
#pragma unroll
    for (int k = 0; k < 128; ++k) acc = fmaf(W3[j * 128 + k], Wl[k], acc);
    w3l[j] = acc;
    if (j == 0) {
        float beta = bl[0];
        for (int f = 0; f < 128; ++f) beta = fmaf(b3[f], Wl[f], beta);
        w3l[64] = beta;
    }
}

// ---------------- L1 GEMM: t1p = (x@W1)*dinv[row], slice-major output ----------------
__global__ void gemm1_kernel(const float* __restrict__ X, const float* __restrict__ W,
                             const float* __restrict__ dinv, float* __restrict__ T, int N) {
    __shared__ float Ws[F_IN * H1];
    for (int t = threadIdx.x; t < F_IN * H1; t += blockDim.x) Ws[t] = W[t];
    __syncthreads();
    constexpr int ROWS = TPB / H1;  // 8
    const int c = threadIdx.x % H1;
    const int r = threadIdx.x / H1;
    for (int base = blockIdx.x * ROWS; base < N; base += gridDim.x * ROWS) {
        int row = base + r;
        if (row >= N) continue;
        const float4* xr = reinterpret_cast<const float4*>(X + (size_t)row * F_IN);
        float acc = 0.0f;
#pragma unroll
        for (int k4 = 0; k4 < F_IN / 4; ++k4) {
            float4 xv = xr[k4];
            acc = fmaf(xv.x, Ws[(k4 * 4 + 0) * H1 + c], acc);
            acc = fmaf(xv.y, Ws[(k4 * 4 + 1) * H1 + c], acc);
            acc = fmaf(xv.z, Ws[(k4 * 4 + 2) * H1 + c], acc);
            acc = fmaf(xv.w, Ws[(k4 * 4 + 3) * H1 + c], acc);
        }
        T[((size_t)(c >> 3) * N + row) * 8 + (c & 7)] = acc * dinv[row];
    }
}

// ---------------- slice-classed CSR gather (8 lanes per node, class = blockIdx&3) --------
// HASBIAS: out = relu(acc*dv + b)*dv (pass 1); else out = acc*dv (pass 2 -> s1)
template <bool HASBIAS>
__global__ void gather_s(const int* __restrict__ rowptr, const int* __restrict__ degi,
                         const int* __restrict__ csr, const float* __restrict__ dinv,
                         const float* __restrict__ b, const float* __restrict__ Tin,
                         float* __restrict__ Tout, int N) {
    const int cls = blockIdx.x & 3;
    const int b4 = blockIdx.x >> 2;
    const int nb4 = gridDim.x >> 2;
    const int f = threadIdx.x & 7;
    const int cl = threadIdx.x >> 3;  // cluster [0,32)
    const float* __restrict__ tab = Tin + (size_t)cls * N * 8;
    float* __restrict__ outp = Tout + (size_t)cls * N * 8;
    const float bias = HASBIAS ? b[cls * 8 + f] : 0.0f;
    for (int node = b4 * 32 + cl; node < N; node += nb4 * 32) {
        float dv = dinv[node];
        float acc = tab[(size_t)node * 8 + f];  // self (prescaled)
        int j = rowptr[node];
        int end = j + degi[node];
        for (; j < end; j += 8) {
            int myIdx = j + f;
            int sidx = (myIdx < end) ? csr[myIdx] : -1;
#pragma unroll
            for (int k = 0; k < 8; ++k) {
                int s = __shfl(sidx, k, 8);
                if (s >= 0) acc += tab[(size_t)s * 8 + f];
            }
        }
        float v;
        if (HASBIAS) v = fmaxf(fmaf(acc, dv, bias), 0.0f) * dv;
        else         v = acc * dv;
        outp[(size_t)node * 8 + f] = v;
    }
}

// ---------------- gemm2 + head fold: zp = relu(s1@W2+b2).w3l * dv ----------------
__global__ void gemm2z_kernel(const float* __restrict__ S1s, const float* __restrict__ W2,
                              const float* __restrict__ b2, const float* __restrict__ w3l,
                              const float* __restrict__ dinv, float* __restrict__ zp, int N) {
    __shared__ float W2s[H1 * 64];
    __shared__ float bw[64];
    __shared__ float wl[64];
    for (int t = threadIdx.x; t < H1 * 64; t += blockDim.x) W2s[t] = W2[t];
    if (threadIdx.x < 64) {
        bw[threadIdx.x] = b2[threadIdx.x];
        wl[threadIdx.x] = w3l[threadIdx.x];
    }
    __syncthreads();
    int node = blockIdx.x * (TPB / 32) + (threadIdx.x >> 5);
    int f = threadIdx.x & 31;
    if (node >= N) return;
    float s1 = S1s[((size_t)(f >> 3) * N + node) * 8 + (f & 7)];
    float d0 = bw[f], d1 = bw[f + 32];
#pragma unroll
    for (int k = 0; k < H1; ++k) {
        float sv = __shfl(s1, k, 32);
        d0 = fmaf(sv, W2s[k * 64 + f], d0);
        d1 = fmaf(sv, W2s[k * 64 + f + 32], d1);
    }
    float p = fmaxf(d0, 0.0f) * wl[f] + fmaxf(d1, 0.0f) * wl[f + 32];
#pragma unroll
    for (int o = 16; o > 0; o >>= 1) p += __shfl_down(p, o, 32);
    if (f == 0) zp[node] = p * dinv[node];
}

// ---------------- pass 3 scalar gather fused with segment-mean pooling ----------------
__global__ void gather_z_pool(const int* __restrict__ rowptr, const int* __restrict__ degi,
                              const int* __restrict__ csr_src, const float* __restrict__ dinv,
                              const float* __restrict__ zp, const int* __restrict__ batch,
                              float* __restrict__ sums, float* __restrict__ cnt, int N, int G) {
    __shared__ float accS[TPB];
    __shared__ float cntS[TPB];
    accS[threadIdx.x] = 0.0f;
    cntS[threadIdx.x] = 0.0f;
    __syncthreads();
    int i = blockIdx.x * TPB + threadIdx.x;
    int first = blockIdx.x * TPB;
    int b0 = batch[first < N ? first : (N - 1)];
    if (i < N) {
        float acc = zp[i];  // self (prescaled)
        int j = rowptr[i];
        int end = j + degi[i];
        for (; j + 1 < end; j += 2) acc += zp[csr_src[j]] + zp[csr_src[j + 1]];
        if (j < end) acc += zp[csr_src[j]];
        float val = acc * dinv[i];
        int off = batch[i] - b0;
        if (off < TPB) {
            atomicAdd(&accS[off], val);
            atomicAdd(&cntS[off], 1.0f);
        } else {
            atomicAdd(&sums[batch[i]], val);
            atomicAdd(&cnt[batch[i]], 1.0f);
        }
    }
    __syncthreads();
    int g = b0 + threadIdx.x;
    if (g < G) {
        if (accS[threadIdx.x] != 0.0f) atomicAdd(&sums[g], accS[threadIdx.x]);
        if (cntS[threadIdx.x] != 0.0f) atomicAdd(&cnt[g], cntS[threadIdx.x]);
    }
}

__global__ void out_kernel(const float* __restrict__ sums, const float* __restrict__ cnt,
                           const float* __restrict__ w3l, float* __restrict__ out, int G) {
    int g = blockIdx.x * blockDim.x + threadIdx.x;
    if (g < G) out[g] = sums[g] / fmaxf(cnt[g], 1.0f) + w3l[64];
}

static inline int grid_for(unsigned total, int cap = 8192) {
    unsigned g = (total + TPB - 1) / TPB;
    return (int)(g < (unsigned)cap ? g : (unsigned)cap);
}

extern "C" void kernel_launch(void* const* d_in, const int* in_sizes, int n_in,
                              void* d_out, int out_size, void* d_ws, size_t ws_size,
                              hipStream_t stream) {
    const float* x     = (const float*)d_in[0];
    const int*   ei    = (const int*)d_in[1];
    const int*   batch = (const int*)d_in[2];
    const float* W1    = (const float*)d_in[3];
    const float* b1    = (const float*)d_in[4];
    const float* W2    = (const float*)d_in[5];
    const float* b2    = (const float*)d_in[6];
    const float* W3    = (const float*)d_in[7];
    const float* b3    = (const float*)d_in[8];
    const float* Wl    = (const float*)d_in[9];
    const float* bl    = (const float*)d_in[10];
    float* out = (float*)d_out;

    const int N = in_sizes[0] / F_IN;  // 100000
    const int E = in_sizes[1] / 2;     // 1600000
    const int G = out_size;            // 1024
    const int* src = ei;
    const int* dst = ei + E;
    const int nb = (N + TPB - 1) / TPB;  // scan blocks (391 <= 512)

    // workspace layout
    int*   degi    = (int*)d_ws;                       // N
    int*   rowptr  = degi + N;                         // N
    int*   cursor  = rowptr + N;                       // N
    int*   bsum    = cursor + N;                       // 512
    int*   csr_src = bsum + 512;                       // E
    float* dinv    = (float*)(csr_src + E);            // N
    float* t1p     = dinv + N;                         // N*32 (slice-major)
    float* g1p     = t1p + (size_t)N * H1;             // N*32 (slice-major)
    float* s1s     = g1p + (size_t)N * H1;             // N*32 (slice-major)
    float* zp      = s1s + (size_t)N * H1;             // N
    float* w3l     = zp + N;                           // 72
    float* sums    = w3l + 72;                         // G
    float* cnt     = sums + G;                         // G

    hipMemsetAsync(degi, 0, (size_t)N * sizeof(int), stream);
    hipMemsetAsync(sums, 0, (size_t)2 * G * sizeof(float), stream);

    // degree -> CSR rowptr/cursor + dinv
    deg_kernel<<<grid_for(E), TPB, 0, stream>>>(dst, degi, E);
    scan1<<<nb, TPB, 0, stream>>>(degi, bsum, N);
    scan2<<<1, 512, 0, stream>>>(bsum, nb);
    scan3<<<nb, TPB, 0, stream>>>(degi, bsum, rowptr, cursor, dinv, N);
    fill_bucketed<<<2048, TPB, 0, stream>>>(src, dst, cursor, csr_src, E, N);

    // fold last layer + head
    prep_kernel<<<1, 64, 0, stream>>>(W3, b3, Wl, bl, w3l);

    // L1: t1p = (x@W1)*dinv  (slice-major)
    gemm1_kernel<<<grid_for((unsigned)N * H1), TPB, 0, stream>>>(x, W1, dinv, t1p, N);

    // pass 1: g1p = relu(gather(t1p)*dv + b1)*dv   (slice-classed)
    gather_s<true><<<4096, TPB, 0, stream>>>(rowptr, degi, csr_src, dinv, b1, t1p, g1p, N);

    // pass 2: s1 = gather(g1p)*dv                  (slice-classed)
    gather_s<false><<<4096, TPB, 0, stream>>>(rowptr, degi, csr_src, dinv, nullptr, g1p, s1s, N);

    // gemm2 + head fold -> zp
    gemm2z_kernel<<<(N + 7) / 8, TPB, 0, stream>>>(s1s, W2, b2, w3l, dinv, zp, N);

    // pass 3: scalar gather + segment mean
    gather_z_pool<<<(N + TPB - 1) / TPB, TPB, 0, stream>>>(rowptr, degi, csr_src, dinv, zp,
                                                           batch, sums, cnt, N, G);
    out_kernel<<<(G + TPB - 1) / TPB, TPB, 0, stream>>>(sums, cnt, w3l, out, G);
}